// Round 4
// baseline (576.762 us; speedup 1.0000x reference)
//
#include <hip/hip_runtime.h>
#include <stdint.h>

#define N_ROWS 4096
#define F_DIM  2048
#define B_DIM  2048
#define K_DIM  4096   // F (h part) + B (behavior part)
#define BK     32     // k per pipeline stage

typedef __attribute__((ext_vector_type(8)))  __bf16 bf16x8;
typedef __attribute__((ext_vector_type(16))) float  f32x16;
typedef unsigned short u16;

__device__ __forceinline__ u16 f2bf(float x) {
  unsigned int u = __float_as_uint(x);
  u += 0x7fffu + ((u >> 16) & 1u);   // RNE
  return (u16)(u >> 16);
}

__device__ __forceinline__ void async_copy16(const void* g, void* l) {
  __builtin_amdgcn_global_load_lds(
      (const __attribute__((address_space(1))) void*)g,
      (__attribute__((address_space(3))) void*)l, 16, 0, 0);
}

__device__ __forceinline__ float sigmoid_f(float x) {
  return 1.0f / (1.0f + __expf(-x));
}
__device__ __forceinline__ float tanh_f(float x) {
  float e2 = __expf(2.0f * x);
  return 1.0f - 2.0f / (e2 + 1.0f);
}

// ---------------- pack_x: Xc[n][k] = bf16( k<F ? h0[n][k] : behavior[n][k-F] )
__global__ __launch_bounds__(256) void pack_x_kernel(
    const float* __restrict__ h0, const float* __restrict__ behavior,
    u16* __restrict__ Xc)
{
  int tid = blockIdx.x * 256 + threadIdx.x;  // one thread = 8 consecutive k
  int row = tid >> 9;                        // K_DIM/8 = 512 octets per row
  int k0  = (tid & 511) * 8;
  const float* src = (k0 < F_DIM) ? (h0 + (size_t)row * F_DIM + k0)
                                  : (behavior + (size_t)row * B_DIM + (k0 - F_DIM));
  const float4* s4 = (const float4*)src;
  float4 a = s4[0], b = s4[1];
  uint4 o;
  o.x = (unsigned)f2bf(a.x) | ((unsigned)f2bf(a.y) << 16);
  o.y = (unsigned)f2bf(a.z) | ((unsigned)f2bf(a.w) << 16);
  o.z = (unsigned)f2bf(b.x) | ((unsigned)f2bf(b.y) << 16);
  o.w = (unsigned)f2bf(b.z) | ((unsigned)f2bf(b.w) << 16);
  *(uint4*)(Xc + (size_t)tid * 8) = o;
}

// ---------------- pack_w v3: WT[g][f][k] = bf16( k<F ? W?_h[k][f] : W?_x[k-F][f] )
__global__ __launch_bounds__(256) void pack_w_kernel(
    const float* __restrict__ wi_h, const float* __restrict__ wi_x,
    const float* __restrict__ wf_h, const float* __restrict__ wf_x,
    const float* __restrict__ wg_h, const float* __restrict__ wg_x,
    const float* __restrict__ wo_h, const float* __restrict__ wo_x,
    u16* __restrict__ WT)
{
  __shared__ float tileT[32 * 65];  // tileT[f_local][k_local], pad 65
  int g = blockIdx.z;
  const float* Wh = (g == 0) ? wi_h : (g == 1) ? wf_h : (g == 2) ? wg_h : wo_h;
  const float* Wx = (g == 0) ? wi_x : (g == 1) ? wf_x : (g == 2) ? wg_x : wo_x;
  int fb = blockIdx.x * 32;   // feature tile base
  int kb = blockIdx.y * 64;   // k tile base (block-uniform h/x split: 64 | 2048)
  const float* W = (kb < F_DIM) ? Wh : Wx;
  int kofs = (kb < F_DIM) ? kb : (kb - F_DIM);

  int t  = threadIdx.x;
  int c4 = t & 7;          // float4 column within f-tile (8*4 = 32 f)
  int kr = t >> 3;         // 0..31
#pragma unroll
  for (int p = 0; p < 2; ++p) {
    int k_l = kr + p * 32;  // 0..63
    float4 v = *(const float4*)(W + (size_t)(kofs + k_l) * F_DIM + fb + c4 * 4);
    tileT[(c4 * 4 + 0) * 65 + k_l] = v.x;
    tileT[(c4 * 4 + 1) * 65 + k_l] = v.y;
    tileT[(c4 * 4 + 2) * 65 + k_l] = v.z;
    tileT[(c4 * 4 + 3) * 65 + k_l] = v.w;
  }
  __syncthreads();
  {
    int f_l = t >> 3;            // 0..31
    int k8  = (t & 7) * 8;       // 0..56
    const float* s = tileT + f_l * 65 + k8;
    uint4 o;
    o.x = (unsigned)f2bf(s[0]) | ((unsigned)f2bf(s[1]) << 16);
    o.y = (unsigned)f2bf(s[2]) | ((unsigned)f2bf(s[3]) << 16);
    o.z = (unsigned)f2bf(s[4]) | ((unsigned)f2bf(s[5]) << 16);
    o.w = (unsigned)f2bf(s[6]) | ((unsigned)f2bf(s[7]) << 16);
    *(uint4*)(WT + ((size_t)g * F_DIM + fb + f_l) * K_DIM + kb + k8) = o;
  }
}

// ---------------- fused 4-gate GEMM + LSTM epilogue (v4: explicit dbuf pipeline)
// Block: 256 thr = 4 waves, output tile 128 rows x (4 gates x 64 f).
// Waves 2x2: rw = w&1 rows, fh = w>>1 f-half. Wave tile 64x128 eff, MFMA 32x32x16.
// K-loop: BK=32 per stage, DOUBLE-BUFFERED LDS (2 x 24 KB = 48 KB, 2 blocks/CU).
// Per iter: issue 6 global_load_lds into buf[p^1] (tile kt+1), compute buf[p],
// ONE __syncthreads. The compiler's vmcnt(0) drain at the barrier waits on
// copies that had the whole compute phase in flight -> latency hidden.
// Swizzle: physical slot = logical octet ^ ((row>>1)&3); rows are 64 B so this
// spreads a wave's b128 read across all 32 banks at the structural min 8/bank.
__global__ __launch_bounds__(256, 2) void lstm_gemm_kernel(
    const u16* __restrict__ Xc, const u16* __restrict__ WT,
    const float* __restrict__ c0,
    const float* __restrict__ bi, const float* __restrict__ bff,
    const float* __restrict__ bg, const float* __restrict__ bo,
    float* __restrict__ out)
{
  __shared__ u16 As[2][128 * BK];      // 2 x 8 KB
  __shared__ u16 Bs[2][4 * 64 * BK];   // 2 x 16 KB

  const int tid  = threadIdx.x;
  const int lane = tid & 63;
  const int wv   = tid >> 6;
  const int bm   = blockIdx.x;  // rows bm*128 (x fast-varying -> B-tile L2 reuse)
  const int bn   = blockIdx.y;  // f-cols bn*64

  const int rw = wv & 1;        // row half
  const int fh = wv >> 1;       // f half
  const int l31  = lane & 31;
  const int half = lane >> 5;

  // ---- staging descriptors: chunk c -> row r = c>>2, slot s = c&3,
  // fetch global octet o = s ^ ((r>>1)&3) so physical slot s holds it.
  const u16* agp[2];
  const u16* bgp[4];
#pragma unroll
  for (int j = 0; j < 2; ++j) {  // A: 512 chunks over 128 rows
    int c = j * 256 + tid;
    int r = c >> 2, o = (c & 3) ^ ((r >> 1) & 3);
    agp[j] = Xc + (size_t)(bm * 128 + r) * K_DIM + o * 8;
  }
#pragma unroll
  for (int j = 0; j < 4; ++j) {  // B: 1024 chunks over 256 f-rows (gate-major)
    int c = j * 256 + tid;
    int r = c >> 2, o = (c & 3) ^ ((r >> 1) & 3);
    int g = r >> 6, fl = r & 63;
    bgp[j] = WT + ((size_t)g * F_DIM + bn * 64 + fl) * K_DIM + o * 8;
  }
  const unsigned ubase = (unsigned)(tid & ~63) * 16u;  // wave-uniform LDS byte offset

  f32x16 acc[4][2];
#pragma unroll
  for (int g = 0; g < 4; ++g)
#pragma unroll
    for (int rh = 0; rh < 2; ++rh)
#pragma unroll
      for (int r = 0; r < 16; ++r) acc[g][rh][r] = 0.f;

  // ---- prologue: stage tile 0 into buffer 0
#pragma unroll
  for (int j = 0; j < 2; ++j)
    async_copy16(agp[j], (char*)As[0] + j * 4096 + ubase);
#pragma unroll
  for (int j = 0; j < 4; ++j)
    async_copy16(bgp[j], (char*)Bs[0] + j * 4096 + ubase);
#pragma unroll
  for (int j = 0; j < 2; ++j) agp[j] += BK;
#pragma unroll
  for (int j = 0; j < 4; ++j) bgp[j] += BK;
  __syncthreads();  // vmcnt(0) drain -> tile 0 resident

  const int swq = (l31 >> 1) & 3;
  const int mrow = rw * 64 + l31;       // + rh*32
  const int frow = fh * 32 + l31;

  for (int kt = 0; kt < 128; ++kt) {
    const int p = kt & 1;
    if (kt + 1 < 128) {   // issue next tile's copies BEFORE compute (uniform branch)
#pragma unroll
      for (int j = 0; j < 2; ++j)
        async_copy16(agp[j], (char*)As[p ^ 1] + j * 4096 + ubase);
#pragma unroll
      for (int j = 0; j < 4; ++j)
        async_copy16(bgp[j], (char*)Bs[p ^ 1] + j * 4096 + ubase);
#pragma unroll
      for (int j = 0; j < 2; ++j) agp[j] += BK;
#pragma unroll
      for (int j = 0; j < 4; ++j) bgp[j] += BK;
    }

#pragma unroll
    for (int c16 = 0; c16 < 2; ++c16) {  // two k-chunks of 16 within BK=32
      const int oct = c16 * 2 + half;
      const int sw  = oct ^ swq;
      bf16x8 af[2];
#pragma unroll
      for (int rh = 0; rh < 2; ++rh)
        af[rh] = *(const bf16x8*)(&As[p][(mrow + rh * 32) * BK + sw * 8]);
      bf16x8 bfr[4];
#pragma unroll
      for (int g = 0; g < 4; ++g)
        bfr[g] = *(const bf16x8*)(&Bs[p][(g * 64 + frow) * BK + sw * 8]);
#pragma unroll
      for (int g = 0; g < 4; ++g)
#pragma unroll
        for (int rh = 0; rh < 2; ++rh)
          acc[g][rh] = __builtin_amdgcn_mfma_f32_32x32x16_bf16(
              af[rh], bfr[g], acc[g][rh], 0, 0, 0);
    }
    __syncthreads();  // everyone done reading buf[p]; drains vmcnt -> buf[p^1] ready
  }

  // ---- epilogue: 32x32 C/D layout: col = lane&31, row = (r&3) + 8*(r>>2) + 4*half
  {
    int f = bn * 64 + fh * 32 + l31;
    float b0 = bi[f], b1 = bff[f], b2 = bg[f], b3 = bo[f];
#pragma unroll
    for (int rh = 0; rh < 2; ++rh) {
      int row_base = bm * 128 + rw * 64 + rh * 32 + 4 * half;
#pragma unroll
      for (int r = 0; r < 16; ++r) {
        int row = row_base + (r & 3) + 8 * (r >> 2);
        size_t idx = (size_t)row * F_DIM + f;
        float pi = acc[0][rh][r] + b0;
        float pf = acc[1][rh][r] + b1;
        float pg = acc[2][rh][r] + b2;
        float po = acc[3][rh][r] + b3;
        float iv = sigmoid_f(pi);
        float fv = sigmoid_f(pf);
        float gv = tanh_f(pg);
        float ov = sigmoid_f(po);
        float cv = fv * c0[idx] + iv * gv;
        out[idx] = ov * tanh_f(cv);
      }
    }
  }
}

extern "C" void kernel_launch(void* const* d_in, const int* in_sizes, int n_in,
                              void* d_out, int out_size, void* d_ws, size_t ws_size,
                              hipStream_t stream) {
  const float* behavior = (const float*)d_in[0];
  const float* h0       = (const float*)d_in[1];
  const float* c0       = (const float*)d_in[2];
  const float* Wi_h     = (const float*)d_in[3];
  const float* Wi_x     = (const float*)d_in[4];
  const float* bi       = (const float*)d_in[5];
  const float* Wf_h     = (const float*)d_in[6];
  const float* Wf_x     = (const float*)d_in[7];
  const float* bf       = (const float*)d_in[8];
  const float* Wg_h     = (const float*)d_in[9];
  const float* Wg_x     = (const float*)d_in[10];
  const float* bg       = (const float*)d_in[11];
  const float* Wo_h     = (const float*)d_in[12];
  const float* Wo_x     = (const float*)d_in[13];
  const float* bo       = (const float*)d_in[14];
  float* out = (float*)d_out;

  // workspace: Xc (32 MB bf16) + WT (64 MB bf16) = ~96 MiB
  u16* Xc = (u16*)d_ws;
  u16* WT = Xc + (size_t)N_ROWS * K_DIM;

  pack_x_kernel<<<dim3(N_ROWS * (K_DIM / 8) / 256), 256, 0, stream>>>(h0, behavior, Xc);
  pack_w_kernel<<<dim3(F_DIM / 32, K_DIM / 64, 4), 256, 0, stream>>>(
      Wi_h, Wi_x, Wf_h, Wf_x, Wg_h, Wg_x, Wo_h, Wo_x, WT);
  lstm_gemm_kernel<<<dim3(N_ROWS / 128, F_DIM / 64), 256, 0, stream>>>(
      Xc, WT, c0, bi, bf, bg, bo, out);
}